// Round 8
// baseline (1473.761 us; speedup 1.0000x reference)
//
#include <hip/hip_runtime.h>
#include <hip/hip_bf16.h>
#include <math.h>

#define LRELU_SLOPE 0.2f
typedef __hip_bfloat16 bf16;
typedef __hip_bfloat162 bf16x2;

typedef short s8v __attribute__((ext_vector_type(8)));   // 8 bf16 (4 VGPRs)
typedef short s4v __attribute__((ext_vector_type(4)));   // 4 bf16 (2 VGPRs)
typedef float f4v __attribute__((ext_vector_type(4)));   // MFMA acc
typedef int   i4v __attribute__((ext_vector_type(4)));
typedef unsigned int u4v __attribute__((ext_vector_type(4)));

__device__ __forceinline__ float lrelu(float v) { return v > 0.f ? v : LRELU_SLOPE * v; }
__device__ __forceinline__ float b2f(short b) {
  return __uint_as_float(((unsigned)(unsigned short)b) << 16);
}

__device__ __forceinline__ void st2(float* p, float x, float y) {
  *(float2*)p = float2{x, y};
}

// ---- streaming store (sc1 + nt): measured NEUTRAL (R4), kept as harmless ----
__device__ __forceinline__ u4v make_srd(const void* p) {
  u4v r;
  unsigned long long a = (unsigned long long)p;
  r.x = (unsigned)a; r.y = (unsigned)(a >> 32);
  r.z = 0xFFFFFFFFu;          // num_records: disable bounds check
  r.w = 0x00020000u;          // raw dword access
  return r;
}
__device__ __forceinline__ void bstore16_nt(u4v srd, int byteoff, i4v d) {
  asm volatile("buffer_store_dwordx4 %0, %1, %2, 0 offen sc1 nt"
               :: "v"(d), "v"(byteoff), "s"(srd));
}

// ---------------- zero helper (avoid hipMemsetAsync in capture) ----------------

__global__ void k_zero(unsigned int* __restrict__ p, long n) {
  long i = (long)blockIdx.x * blockDim.x + threadIdx.x;
  if (i < n) p[i] = 0u;
}

__global__ void k_zero_out(float* __restrict__ out, int n) {
  int i = blockIdx.x * blockDim.x + threadIdx.x;
  if (i < n) out[i] = 0.f;
}

// ---------------- dtype prep ----------------

// vectorized: 8 floats -> 8 bf16 per thread (N*128 is a multiple of 8)
__global__ void k_cvt(const float* __restrict__ x, bf16* __restrict__ xb, long n8) {
  long i = (long)blockIdx.x * blockDim.x + threadIdx.x;
  if (i >= n8) return;
  const float4* xp = (const float4*)(x + i * 8);
  float4 a = xp[0], b = xp[1];
  s8v v;
  bf16 t;
  t = __float2bfloat16(a.x); v[0] = *(short*)&t;
  t = __float2bfloat16(a.y); v[1] = *(short*)&t;
  t = __float2bfloat16(a.z); v[2] = *(short*)&t;
  t = __float2bfloat16(a.w); v[3] = *(short*)&t;
  t = __float2bfloat16(b.x); v[4] = *(short*)&t;
  t = __float2bfloat16(b.y); v[5] = *(short*)&t;
  t = __float2bfloat16(b.z); v[6] = *(short*)&t;
  t = __float2bfloat16(b.w); v[7] = *(short*)&t;
  *(s8v*)&xb[i * 8] = v;
}

// W[K][NN] (f32) -> fragment-packed B2 (bf16).
// Fragment f = k32*(NN/16) + ct holds the 16x32 tile (cols ct*16..+16,
// k = k32*32..+32) in MFMA B-operand lane order:
//   B2[f*512 + l*8 + j] = W[k32*32 + (l>>4)*8 + j][ct*16 + (l&15)]
// so a wave's bfrag load is ONE fully-coalesced 1KB global load (lane*8 elems).
__global__ void k_tw2(const float* __restrict__ W, bf16* __restrict__ B2, int K, int NN) {
  int tid = blockIdx.x * blockDim.x + threadIdx.x;   // one thread per 8 elems
  int total = (K * NN) >> 3;
  if (tid >= total) return;
  int f = tid >> 6, l = tid & 63;
  int nfr = NN >> 4;
  int k32 = f / nfr, ct = f - k32 * nfr;
  int col = ct * 16 + (l & 15);
  int krow = k32 * 32 + (l >> 4) * 8;
  s8v v;
#pragma unroll
  for (int j = 0; j < 8; ++j) {
    bf16 b = __float2bfloat16(W[(size_t)(krow + j) * NN + col]);
    v[j] = *(short*)&b;
  }
  *(s8v*)&B2[(size_t)tid * 8] = v;
}

// ---------------- preprocessing: counting-sort edges by dst ----------------

__global__ void k_hist(const int* __restrict__ dst, int* __restrict__ deg, int E, int Et) {
  int e = blockIdx.x * blockDim.x + threadIdx.x;
  if (e >= Et) return;
  int d = (e < E) ? dst[e] : (e - E);   // self-loops appended
  atomicAdd(&deg[d], 1);
}

__global__ void k_hist1(const int* __restrict__ idx, int* __restrict__ deg, int n) {
  int i = blockIdx.x * blockDim.x + threadIdx.x;
  if (i < n) atomicAdd(&deg[idx[i]], 1);
}

__global__ void k_scan1(const int* __restrict__ deg, int* __restrict__ offs,
                        int* __restrict__ bsum, int n) {
  __shared__ int sd[256];
  int t = threadIdx.x;
  int base = blockIdx.x * 1024 + t * 4;
  int v[4]; int tsum = 0;
#pragma unroll
  for (int i = 0; i < 4; ++i) { v[i] = (base + i < n) ? deg[base + i] : 0; tsum += v[i]; }
  sd[t] = tsum;
  __syncthreads();
  for (int off = 1; off < 256; off <<= 1) {
    int x = (t >= off) ? sd[t - off] : 0;
    __syncthreads();
    sd[t] += x;
    __syncthreads();
  }
  int excl = sd[t] - tsum;
#pragma unroll
  for (int i = 0; i < 4; ++i) { if (base + i < n) offs[base + i] = excl; excl += v[i]; }
  if (t == 255) bsum[blockIdx.x] = sd[255];
}

// parallel exclusive scan over block sums (nb <= 256 here)
__global__ void k_scan2(int* bsum, int nb) {
  int t = threadIdx.x;
  if (nb > 256) {
    if (t == 0 && blockIdx.x == 0) {
      int run = 0;
      for (int i = 0; i < nb; ++i) { int x = bsum[i]; bsum[i] = run; run += x; }
    }
    return;
  }
  int v = (t < nb) ? bsum[t] : 0;
  int lane = t & 63, wv = t >> 6;
  int s = v;
#pragma unroll
  for (int off = 1; off < 64; off <<= 1) {
    int u = __shfl_up(s, off, 64);
    if (lane >= off) s += u;
  }
  __shared__ int wsum[4];
  if (lane == 63) wsum[wv] = s;
  __syncthreads();
  int add = 0;
  for (int w = 0; w < wv; ++w) add += wsum[w];
  if (t < nb) bsum[t] = add + s - v;   // exclusive
}

__global__ void k_scan3(int* __restrict__ offs, const int* __restrict__ bsum, int n, int total) {
  int t = threadIdx.x;
  int base = blockIdx.x * 1024 + t * 4;
  int add = bsum[blockIdx.x];
#pragma unroll
  for (int i = 0; i < 4; ++i) if (base + i < n) offs[base + i] += add;
  if (blockIdx.x == 0 && t == 0) offs[n] = total;
}

__global__ void k_scatter(const int* __restrict__ src, const int* __restrict__ dst,
                          const int* __restrict__ offs, int* __restrict__ cur,
                          int* __restrict__ ssrc, int E, int Et) {
  int e = blockIdx.x * blockDim.x + threadIdx.x;
  if (e >= Et) return;
  int s, d;
  if (e < E) { s = src[e]; d = dst[e]; } else { s = d = e - E; }
  int pos = offs[d] + atomicAdd(&cur[d], 1);
  ssrc[pos] = s;
}

// ------- tiled MFMA GEMM + FUSED attention-logit epilogue -------
// C[M,NN] = A[M,K] @ W[K,NN], BM=256, 2-phase LDS double-buffer (verified R5).
// NEW (this round): the k_al pass re-read C (154+154+51 MB) just to dot each
// head row with a_src/a_dst. Each y-block covers exactly ONE 128-col head, so
// the dot is computed here from the bf16-ROUNDED acc values (numerically
// identical h to the old k_al path), reduced over the 16 l15 lanes via
// shfl_xor, and atomicAdd'ed into the padded al_s/al_d (zeroed before launch).
// Per wave: 16 rows x 2 values x 2 buffers -> ~2.4M f32 atomics/layer (~k_hist
// scale). Rows >= N are guarded (padding rows produce no atomics).

template <int K, int NN>
__global__ __launch_bounds__(512, 4) void k_gemm_t(const bf16* __restrict__ A,
                                                   const bf16* __restrict__ B2,
                                                   bf16* __restrict__ C,
                                                   const float* __restrict__ as_,
                                                   const float* __restrict__ ad_,
                                                   float* __restrict__ al_s,
                                                   float* __restrict__ al_d,
                                                   int N) {
  constexpr int nk = K / 32;
  constexpr int nfr = NN >> 4;
  constexpr int SP = (NN == 384) ? 4 : 1;            // al padding stride
  __shared__ __align__(16) short sA[2][256 * 32];    // 2 x 16 KB
  int t = threadIdx.x;
  int wv = t >> 6, lane = t & 63;
  int mg = wv >> 1, ng = wv & 1;
  int quad = lane >> 4, l15 = lane & 15;
  size_t bm0 = (size_t)blockIdx.x * 256;
  int hd = (NN == 384) ? blockIdx.y : 0;             // this y-block's head
  int ctb = blockIdx.y * 8 + ng * 4;                 // first 16-col tile

  // staging map: thread t covers slab row sr (+128 for shot 1), chunk p.
  // chunk swizzle c = p ^ (row & 3); row&3 == sr&3 for both shots (128%4==0).
  int sr = t >> 2, p = t & 3;
  int c = p ^ (sr & 3);
  const bf16* g0 = A + (bm0 + sr) * (size_t)K + c * 8;
  const bf16* g1 = g0 + (size_t)128 * K;
  const bf16* Bp = B2 + ((size_t)ctb << 9) + lane * 8;

  f4v acc[4][4];
#pragma unroll
  for (int ms = 0; ms < 4; ++ms)
#pragma unroll
    for (int bn = 0; bn < 4; ++bn) acc[ms][bn] = f4v{0, 0, 0, 0};

#define STAGE(step, buf)                                                        \
  do {                                                                          \
    __builtin_amdgcn_global_load_lds(                                           \
        (const __attribute__((address_space(1))) void*)(g0 + (step) * 32),      \
        (__attribute__((address_space(3))) void*)((char*)sA[buf] + wv * 1024),  \
        16, 0, 0);                                                              \
    __builtin_amdgcn_global_load_lds(                                           \
        (const __attribute__((address_space(1))) void*)(g1 + (step) * 32),      \
        (__attribute__((address_space(3))) void*)((char*)sA[buf] + 8192 + wv * 1024), \
        16, 0, 0);                                                              \
  } while (0)

  STAGE(0, 0);
  __syncthreads();                       // vmcnt(0): tile 0 landed

  for (int ik = 0; ik < nk; ++ik) {
    int cur = ik & 1;
    if (ik + 1 < nk) STAGE(ik + 1, cur ^ 1);   // issue next tile FIRST

    const char* sb = (const char*)sA[cur];
    s8v af[4];
#pragma unroll
    for (int ms = 0; ms < 4; ++ms) {
      int row = mg * 64 + ms * 16 + l15;
      int pos = quad ^ (row & 3);
      af[ms] = *(const s8v*)(sb + row * 64 + pos * 16);
    }
    s8v pb[4];
#pragma unroll
    for (int bn = 0; bn < 4; ++bn)
      pb[bn] = *(const s8v*)(Bp + ((size_t)(ik * nfr + bn) << 9));
#pragma unroll
    for (int ms = 0; ms < 4; ++ms)
#pragma unroll
      for (int bn = 0; bn < 4; ++bn)
        acc[ms][bn] = __builtin_amdgcn_mfma_f32_16x16x32_bf16(af[ms], pb[bn], acc[ms][bn], 0, 0, 0);

    __syncthreads();                     // drain stage(t+1) + guard buffer reuse
  }
#undef STAGE

  // attention vectors for this lane's 4 columns (within-head col = (ng*4+bn)*16+l15)
  float asv[4], adv[4];
#pragma unroll
  for (int bn = 0; bn < 4; ++bn) {
    int cwh = (ng * 4 + bn) * 16 + l15;
    asv[bn] = as_[hd * 128 + cwh];
    adv[bn] = ad_[hd * 128 + cwh];
  }

  // C/D layout: col = lane&15, row = quad*4 + reg  [m89/m91 verified]
  // Epilogue: store C (bf16) and dot the ROUNDED values with as/ad; reduce
  // over l15 lanes; lane l15==0 atomically accumulates per-row logits.
#pragma unroll
  for (int ms = 0; ms < 4; ++ms) {
#pragma unroll
    for (int r = 0; r < 4; ++r) {
      size_t rown = bm0 + mg * 64 + ms * 16 + quad * 4 + r;
      float ps = 0.f, pd = 0.f;
#pragma unroll
      for (int bn = 0; bn < 4; ++bn) {
        int coln = (ctb + bn) * 16 + l15;
        bf16 b = __float2bfloat16(acc[ms][bn][r]);
        C[rown * NN + coln] = b;
        float hv = b2f(*(short*)&b);
        ps += hv * asv[bn];
        pd += hv * adv[bn];
      }
#pragma unroll
      for (int off = 1; off <= 8; off <<= 1) {
        ps += __shfl_xor(ps, off, 64);
        pd += __shfl_xor(pd, off, 64);
      }
      if (l15 == 0 && rown < (size_t)N) {
        atomicAdd(&al_s[rown * SP + hd], ps);
        atomicAdd(&al_d[rown * SP + hd], pd);
      }
    }
  }
}

// -------- fused segment-softmax + weighted aggregation: one wave per node --------
// (stable at ~241us/layer across 6 rounds; at the random-gather L2-miss floor.)

template <int CPL> struct HVec;
template <> struct HVec<8> { typedef s8v T; };
template <> struct HVec<4> { typedef s4v T; };

template <int H, typename OT>
__global__ __launch_bounds__(256) void k_attn_agg(const bf16* __restrict__ hbuf,
                           const int* __restrict__ ssrc,
                           const int* __restrict__ offs, const float* __restrict__ al_s,
                           const float* __restrict__ al_d, const float* __restrict__ bias,
                           OT* __restrict__ out, int N) {
  constexpr int SW  = (H > 1) ? 4 : 2;   // stash record (floats)
  constexpr int ROW = H * 128;           // channels per node row
  constexpr int CPL = (H > 1) ? 8 : 4;   // channels per active lane
  constexpr int NL  = ROW / CPL;         // active lanes (48 or 32)
  typedef typename HVec<CPL>::T hvec;

  __shared__ __align__(16) float stash[4][64 * SW];
  int n = (blockIdx.x * blockDim.x + threadIdx.x) >> 6;
  int lane = threadIdx.x & 63;
  if (n >= N) return;
  float* st = stash[threadIdx.x >> 6];
  int start = offs[n], end = offs[n + 1];

  float ald[H];
  if constexpr (H > 1) {
    float4 t = *(const float4*)&al_d[(size_t)n * 4];
    ald[0] = t.x; ald[1] = t.y; ald[2] = t.z;
  } else {
    ald[0] = al_d[n];
  }

  bool act = lane < NL;
  int c0 = act ? lane * CPL : 0;
  int hd_l = c0 >> 7;                    // this lane's head (0 for idle lanes)

  float m[H];
  float den = 0.f;                       // own-head denominator
  float acc[CPL];
#pragma unroll
  for (int hd = 0; hd < H; ++hd) m[hd] = -1e30f;
#pragma unroll
  for (int i = 0; i < CPL; ++i) acc[i] = 0.f;

  for (int cb = start; cb < end; cb += 64) {
    int cl = end - cb; if (cl > 64) cl = 64;
    bool el = lane < cl;
    int mys = el ? ssrc[cb + lane] : 0;
    float ev[H];
    if constexpr (H > 1) {
      float4 av = *(const float4*)&al_s[(size_t)mys * 4];
      ev[0] = av.x; ev[1] = av.y; ev[2] = av.z;
    } else {
      ev[0] = al_s[mys];
    }
#pragma unroll
    for (int hd = 0; hd < H; ++hd)
      ev[hd] = el ? lrelu(ev[hd] + ald[hd]) : -1e30f;

    // chunk max (fused -- no separate max pass over the edges)
    float nm[H];
#pragma unroll
    for (int hd = 0; hd < H; ++hd) {
      float v = ev[hd];
#pragma unroll
      for (int off = 32; off; off >>= 1) v = fmaxf(v, __shfl_xor(v, off, 64));
      nm[hd] = fmaxf(v, m[hd]);
    }
    if (cb > start) {                    // online rescale; wave-uniform branch
      float sc[H];
#pragma unroll
      for (int hd = 0; hd < H; ++hd) sc[hd] = __expf(m[hd] - nm[hd]);
      float so = sc[hd_l];
      den *= so;
#pragma unroll
      for (int i = 0; i < CPL; ++i) acc[i] *= so;
    }
#pragma unroll
    for (int hd = 0; hd < H; ++hd) m[hd] = nm[hd];

    float myex[H];
#pragma unroll
    for (int hd = 0; hd < H; ++hd) myex[hd] = el ? __expf(ev[hd] - m[hd]) : 0.f;

    // stash this chunk's edge records (wave-private region; wave-synchronous)
    __builtin_amdgcn_wave_barrier();
    if constexpr (H > 1) {
      float4 s4{__int_as_float(mys), myex[0], myex[1], myex[2]};
      *(float4*)&st[lane * 4] = s4;
    } else {
      float2 s2{__int_as_float(mys), myex[0]};
      *(float2*)&st[lane * 2] = s2;
    }
    asm volatile("s_waitcnt lgkmcnt(0)" ::: "memory");
    __builtin_amdgcn_wave_barrier();

    for (int r = 0; r < cl; r += 8) {
      int su[8]; float a[8];
#pragma unroll
      for (int u = 0; u < 8; ++u) {
        if constexpr (H > 1) {
          float4 ed = *(const float4*)&st[(r + u) * 4];   // broadcast ds_read_b128
          su[u] = __float_as_int(ed.x);
          a[u] = (hd_l == 0) ? ed.y : ((hd_l == 1) ? ed.z : ed.w);
        } else {
          float2 ed = *(const float2*)&st[(r + u) * 2];
          su[u] = __float_as_int(ed.x);
          a[u] = ed.y;
        }
        den += a[u];                     // tail slots stash a==0
      }
      hvec hv[8];
#pragma unroll
      for (int u = 0; u < 8; ++u)
        hv[u] = *(const hvec*)(hbuf + (size_t)su[u] * ROW + c0);
#pragma unroll
      for (int u = 0; u < 8; ++u)
#pragma unroll
        for (int i = 0; i < CPL; ++i)
          acc[i] += a[u] * b2f(hv[u][i]);
    }
  }

  if (act) {
    float rr = 1.f / (den + 1e-16f);
    u4v srd = make_srd(out);
    int boff = (int)(((size_t)n * ROW + c0) * sizeof(OT));
    if constexpr (sizeof(OT) == 2) {
      union { s8v s; i4v i; } u;
#pragma unroll
      for (int i = 0; i < CPL; ++i) {
        float o = lrelu(acc[i] * rr + bias[c0 + i]);
        bf16 b = __float2bfloat16(o);
        u.s[i] = *(short*)&b;
      }
      bstore16_nt(srd, boff, u.i);
    } else {
      union { float4 f; i4v i; } u;
      u.f.x = lrelu(acc[0] * rr + bias[c0 + 0]);
      u.f.y = lrelu(acc[1] * rr + bias[c0 + 1]);
      u.f.z = lrelu(acc[2] * rr + bias[c0 + 2]);
      u.f.w = lrelu(acc[3] * rr + bias[c0 + 3]);
      bstore16_nt(srd, boff, u.i);
    }
  }
}

// ---------------- global mean pool: one wave per graph, no atomics ----------------

__global__ void k_pool(const float* __restrict__ h, const int* __restrict__ goffs,
                       float* __restrict__ out, int G) {
  int g = (blockIdx.x * blockDim.x + threadIdx.x) >> 6;
  int lane = threadIdx.x & 63;
  if (g >= G) return;
  int s = goffs[g], e = goffs[g + 1];
  float ax = 0.f, ay = 0.f;
  for (int n = s; n < e; ++n) {
    float2 v = *(const float2*)&h[(size_t)n * 128 + lane * 2];
    ax += v.x; ay += v.y;
  }
  float c = fmaxf((float)(e - s), 1.f);
  st2(&out[(size_t)g * 128 + lane * 2], ax / c, ay / c);
}

// ---------------- host launcher ----------------

extern "C" void kernel_launch(void* const* d_in, const int* in_sizes, int n_in,
                              void* d_out, int out_size, void* d_ws, size_t ws_size,
                              hipStream_t stream) {
  const float* x   = (const float*)d_in[0];
  const int*   ei  = (const int*)d_in[1];
  const int*   bat = (const int*)d_in[2];
  const float* W1  = (const float*)d_in[3];
  const float* a1s = (const float*)d_in[4];
  const float* a1d = (const float*)d_in[5];
  const float* b1  = (const float*)d_in[6];
  const float* W2  = (const float*)d_in[7];
  const float* a2s = (const float*)d_in[8];
  const float* a2d = (const float*)d_in[9];
  const float* b2  = (const float*)d_in[10];
  const float* W3  = (const float*)d_in[11];
  const float* a3s = (const float*)d_in[12];
  const float* a3d = (const float*)d_in[13];
  const float* b3  = (const float*)d_in[14];
  float* out = (float*)d_out;

  const int N = in_sizes[2];          // 200000
  const int E = in_sizes[1] / 2;      // 1600000
  const int Et = E + N;               // with self-loops
  const int G = out_size / 128;       // 5000

  const int MB = (N + 255) / 256;     // 256-row GEMM blocks
  const int Mpad = MB * 256;          // padded rows (tail rows are owned garbage)

  // ---- workspace carve (bf16 intermediates; buffers padded to Mpad rows) ----
  char* p = (char*)d_ws;
  auto carve = [&](size_t bytes) { void* r = (void*)p; p += (bytes + 255) & ~(size_t)255; return r; };
  bf16*  bufA   = (bf16*)carve((size_t)Mpad * 384 * 2);  // agg out / GEMM A; also hosts xb & fp32 layer-3 out
  bf16*  bufB   = (bf16*)carve((size_t)Mpad * 384 * 2);  // GEMM output h
  float* al_s   = (float*)carve((size_t)N * 4 * 4);      // padded to 4 floats/node (N*16 is 256-mult)
  float* al_d   = (float*)carve((size_t)N * 4 * 4);
  int*   ssrc   = (int*)carve((size_t)Et * 4);
  int*   offs   = (int*)carve((size_t)(N + 1) * 4);
  int*   deg    = (int*)carve((size_t)N * 4);
  int*   cur    = (int*)carve((size_t)N * 4);
  int*   bsum   = (int*)carve(4096 * 4);
  int*   gdeg   = (int*)carve((size_t)G * 4);
  int*   goffs  = (int*)carve((size_t)(G + 1) * 4);
  bf16*  Wp1    = (bf16*)carve((size_t)384 * 128 * 2);   // packed B2 buffers
  bf16*  Wp2    = (bf16*)carve((size_t)384 * 384 * 2);
  bf16*  Wp3    = (bf16*)carve((size_t)128 * 384 * 2);
  size_t need = (size_t)(p - (char*)d_ws);

  if (ws_size < need) {
    k_zero_out<<<(out_size + 255) / 256, 256, 0, stream>>>(out, out_size);
    return;
  }

  const int* esrc = ei;
  const int* edst = ei + E;

  int ebl = (Et + 255) / 256;
  int NB = (N + 1023) / 1024;
  int GB = (G + 1023) / 1024;
  int nodeWaveBlocks = (N * 64 + 255) / 256;
  long alWords = (long)N * 8;                       // al_s + al_d (contiguous)
  int alBlocks = (int)((alWords + 255) / 256);

  // ---- prep: weight pack+cast, x cast (xb aliases bufA) ----
  bf16* xb = bufA;
  k_cvt<<<((long)N * 128 / 8 + 255) / 256, 256, 0, stream>>>(x, xb, (long)N * 128 / 8);
  k_tw2<<<(128 * 384 / 8 + 255) / 256, 256, 0, stream>>>(W1, Wp1, 128, 384);
  k_tw2<<<(384 * 384 / 8 + 255) / 256, 256, 0, stream>>>(W2, Wp2, 384, 384);
  k_tw2<<<(384 * 128 / 8 + 255) / 256, 256, 0, stream>>>(W3, Wp3, 384, 128);

  // ---- sort edges by dst ----
  k_zero<<<(N + 255) / 256, 256, 0, stream>>>((unsigned int*)deg, N);
  k_hist<<<ebl, 256, 0, stream>>>(edst, deg, E, Et);
  k_scan1<<<NB, 256, 0, stream>>>(deg, offs, bsum, N);
  k_scan2<<<1, 256, 0, stream>>>(bsum, NB);
  k_scan3<<<NB, 256, 0, stream>>>(offs, bsum, N, Et);
  k_zero<<<(N + 255) / 256, 256, 0, stream>>>((unsigned int*)cur, N);
  k_scatter<<<ebl, 256, 0, stream>>>(esrc, edst, offs, cur, ssrc, E, Et);

  // ---- graph offsets for pool (batch is sorted) ----
  k_zero<<<(G + 255) / 256, 256, 0, stream>>>((unsigned int*)gdeg, G);
  k_hist1<<<(N + 255) / 256, 256, 0, stream>>>(bat, gdeg, N);
  k_scan1<<<GB, 256, 0, stream>>>(gdeg, goffs, bsum, G);
  k_scan2<<<1, 256, 0, stream>>>(bsum, GB);
  k_scan3<<<GB, 256, 0, stream>>>(goffs, bsum, G, N);

  // ---- layer 1: xb[N,128] @ W1 -> bufB[N,384] (+fused al) ----
  k_zero<<<alBlocks, 256, 0, stream>>>((unsigned int*)al_s, alWords);
  k_gemm_t<128, 384><<<dim3(MB, 3), 512, 0, stream>>>(xb, Wp1, bufB, a1s, a1d, al_s, al_d, N);
  k_attn_agg<3, bf16><<<nodeWaveBlocks, 256, 0, stream>>>(bufB, ssrc, offs, al_s, al_d, b1, bufA, N);

  // ---- layer 2: bufA[N,384] @ W2 -> bufB[N,384] (+fused al) ----
  k_zero<<<alBlocks, 256, 0, stream>>>((unsigned int*)al_s, alWords);
  k_gemm_t<384, 384><<<dim3(MB, 3), 512, 0, stream>>>(bufA, Wp2, bufB, a2s, a2d, al_s, al_d, N);
  k_attn_agg<3, bf16><<<nodeWaveBlocks, 256, 0, stream>>>(bufB, ssrc, offs, al_s, al_d, b2, bufA, N);

  // ---- layer 3: bufA[N,384] @ W3 -> bufB[N,128], heads=1, fp32 agg out ----
  k_zero<<<alBlocks, 256, 0, stream>>>((unsigned int*)al_s, alWords);
  k_gemm_t<384, 128><<<dim3(MB, 1), 512, 0, stream>>>(bufA, Wp3, bufB, a3s, a3d, al_s, al_d, N);
  float* out3 = (float*)bufA;
  k_attn_agg<1, float><<<nodeWaveBlocks, 256, 0, stream>>>(bufB, ssrc, offs, al_s, al_d, b3, out3, N);

  // ---- global mean pool: segmented, atomic-free ----
  k_pool<<<(G * 64 + 255) / 256, 256, 0, stream>>>(out3, goffs, out, G);
}

// Round 9
// 1271.336 us; speedup vs baseline: 1.1592x; 1.1592x over previous
//
#include <hip/hip_runtime.h>
#include <hip/hip_bf16.h>
#include <math.h>

#define LRELU_SLOPE 0.2f
typedef __hip_bfloat16 bf16;
typedef __hip_bfloat162 bf16x2;

typedef short s8v __attribute__((ext_vector_type(8)));   // 8 bf16 (4 VGPRs)
typedef short s4v __attribute__((ext_vector_type(4)));   // 4 bf16 (2 VGPRs)
typedef float f4v __attribute__((ext_vector_type(4)));   // MFMA acc
typedef int   i4v __attribute__((ext_vector_type(4)));
typedef unsigned int u4v __attribute__((ext_vector_type(4)));

__device__ __forceinline__ float lrelu(float v) { return v > 0.f ? v : LRELU_SLOPE * v; }
__device__ __forceinline__ float b2f(short b) {
  return __uint_as_float(((unsigned)(unsigned short)b) << 16);
}

__device__ __forceinline__ void st2(float* p, float x, float y) {
  *(float2*)p = float2{x, y};
}

// ---- streaming store (sc1 + nt): measured NEUTRAL (R4), kept as harmless ----
__device__ __forceinline__ u4v make_srd(const void* p) {
  u4v r;
  unsigned long long a = (unsigned long long)p;
  r.x = (unsigned)a; r.y = (unsigned)(a >> 32);
  r.z = 0xFFFFFFFFu;          // num_records: disable bounds check
  r.w = 0x00020000u;          // raw dword access
  return r;
}
__device__ __forceinline__ void bstore16_nt(u4v srd, int byteoff, i4v d) {
  asm volatile("buffer_store_dwordx4 %0, %1, %2, 0 offen sc1 nt"
               :: "v"(d), "v"(byteoff), "s"(srd));
}

// ---------------- zero helper (avoid hipMemsetAsync in capture) ----------------

__global__ void k_zero(unsigned int* __restrict__ p, long n) {
  long i = (long)blockIdx.x * blockDim.x + threadIdx.x;
  if (i < n) p[i] = 0u;
}

__global__ void k_zero_out(float* __restrict__ out, int n) {
  int i = blockIdx.x * blockDim.x + threadIdx.x;
  if (i < n) out[i] = 0.f;
}

// ---------------- dtype prep ----------------

// vectorized: 8 floats -> 8 bf16 per thread (N*128 is a multiple of 8)
__global__ void k_cvt(const float* __restrict__ x, bf16* __restrict__ xb, long n8) {
  long i = (long)blockIdx.x * blockDim.x + threadIdx.x;
  if (i >= n8) return;
  const float4* xp = (const float4*)(x + i * 8);
  float4 a = xp[0], b = xp[1];
  s8v v;
  bf16 t;
  t = __float2bfloat16(a.x); v[0] = *(short*)&t;
  t = __float2bfloat16(a.y); v[1] = *(short*)&t;
  t = __float2bfloat16(a.z); v[2] = *(short*)&t;
  t = __float2bfloat16(a.w); v[3] = *(short*)&t;
  t = __float2bfloat16(b.x); v[4] = *(short*)&t;
  t = __float2bfloat16(b.y); v[5] = *(short*)&t;
  t = __float2bfloat16(b.z); v[6] = *(short*)&t;
  t = __float2bfloat16(b.w); v[7] = *(short*)&t;
  *(s8v*)&xb[i * 8] = v;
}

// W[K][NN] (f32) -> fragment-packed B2 (bf16).
// Fragment f = k32*(NN/16) + ct holds the 16x32 tile (cols ct*16..+16,
// k = k32*32..+32) in MFMA B-operand lane order:
//   B2[f*512 + l*8 + j] = W[k32*32 + (l>>4)*8 + j][ct*16 + (l&15)]
__global__ void k_tw2(const float* __restrict__ W, bf16* __restrict__ B2, int K, int NN) {
  int tid = blockIdx.x * blockDim.x + threadIdx.x;   // one thread per 8 elems
  int total = (K * NN) >> 3;
  if (tid >= total) return;
  int f = tid >> 6, l = tid & 63;
  int nfr = NN >> 4;
  int k32 = f / nfr, ct = f - k32 * nfr;
  int col = ct * 16 + (l & 15);
  int krow = k32 * 32 + (l >> 4) * 8;
  s8v v;
#pragma unroll
  for (int j = 0; j < 8; ++j) {
    bf16 b = __float2bfloat16(W[(size_t)(krow + j) * NN + col]);
    v[j] = *(short*)&b;
  }
  *(s8v*)&B2[(size_t)tid * 8] = v;
}

// ---------------- preprocessing: counting-sort edges by dst ----------------

__global__ void k_hist(const int* __restrict__ dst, int* __restrict__ deg, int E, int Et) {
  int e = blockIdx.x * blockDim.x + threadIdx.x;
  if (e >= Et) return;
  int d = (e < E) ? dst[e] : (e - E);   // self-loops appended
  atomicAdd(&deg[d], 1);
}

__global__ void k_hist1(const int* __restrict__ idx, int* __restrict__ deg, int n) {
  int i = blockIdx.x * blockDim.x + threadIdx.x;
  if (i < n) atomicAdd(&deg[idx[i]], 1);
}

__global__ void k_scan1(const int* __restrict__ deg, int* __restrict__ offs,
                        int* __restrict__ bsum, int n) {
  __shared__ int sd[256];
  int t = threadIdx.x;
  int base = blockIdx.x * 1024 + t * 4;
  int v[4]; int tsum = 0;
#pragma unroll
  for (int i = 0; i < 4; ++i) { v[i] = (base + i < n) ? deg[base + i] : 0; tsum += v[i]; }
  sd[t] = tsum;
  __syncthreads();
  for (int off = 1; off < 256; off <<= 1) {
    int x = (t >= off) ? sd[t - off] : 0;
    __syncthreads();
    sd[t] += x;
    __syncthreads();
  }
  int excl = sd[t] - tsum;
#pragma unroll
  for (int i = 0; i < 4; ++i) { if (base + i < n) offs[base + i] = excl; excl += v[i]; }
  if (t == 255) bsum[blockIdx.x] = sd[255];
}

// parallel exclusive scan over block sums (nb <= 256 here)
__global__ void k_scan2(int* bsum, int nb) {
  int t = threadIdx.x;
  if (nb > 256) {
    if (t == 0 && blockIdx.x == 0) {
      int run = 0;
      for (int i = 0; i < nb; ++i) { int x = bsum[i]; bsum[i] = run; run += x; }
    }
    return;
  }
  int v = (t < nb) ? bsum[t] : 0;
  int lane = t & 63, wv = t >> 6;
  int s = v;
#pragma unroll
  for (int off = 1; off < 64; off <<= 1) {
    int u = __shfl_up(s, off, 64);
    if (lane >= off) s += u;
  }
  __shared__ int wsum[4];
  if (lane == 63) wsum[wv] = s;
  __syncthreads();
  int add = 0;
  for (int w = 0; w < wv; ++w) add += wsum[w];
  if (t < nb) bsum[t] = add + s - v;   // exclusive
}

__global__ void k_scan3(int* __restrict__ offs, const int* __restrict__ bsum, int n, int total) {
  int t = threadIdx.x;
  int base = blockIdx.x * 1024 + t * 4;
  int add = bsum[blockIdx.x];
#pragma unroll
  for (int i = 0; i < 4; ++i) if (base + i < n) offs[base + i] += add;
  if (blockIdx.x == 0 && t == 0) offs[n] = total;
}

__global__ void k_scatter(const int* __restrict__ src, const int* __restrict__ dst,
                          const int* __restrict__ offs, int* __restrict__ cur,
                          int* __restrict__ ssrc, int E, int Et) {
  int e = blockIdx.x * blockDim.x + threadIdx.x;
  if (e >= Et) return;
  int s, d;
  if (e < E) { s = src[e]; d = dst[e]; } else { s = d = e - E; }
  int pos = offs[d] + atomicAdd(&cur[d], 1);
  ssrc[pos] = s;
}

// ------- tiled MFMA GEMM (BM=256, 2-phase) + LDS-staged epilogue -------
// Main loop verified R5/R7. Fixes from R6's counters:
//  * 4-way LDS conflict on A ds_read (3.6M measured): swizzle now includes
//    ((row>>2)&3) on BOTH the staged source chunk and the read pos -> 2-way
//    (free, m136).
//  * WRITE 300MB for 154MB C (partial 32B line stores): C now staged through
//    LDS (two 128-row phases, 272B row stride = 2-way-free writes, 16B-aligned
//    reads) and stored as full-line dwordx4 (8 threads = one 128B line).
//  * k_al eliminated WITHOUT R6's atomics: each y-block covers exactly one
//    head, and the read-out thread holds 8 contiguous rounded-bf16 C values of
//    one row -> dot with as/ad, shfl-reduce over the row's 16 lanes, ONE plain
//    store to al_s/al_d (no zero-init, no contention). Same numerics as k_al.
//  * y-fastest 1D grid: the NY y-siblings sharing an A panel dispatch
//    adjacently -> A re-reads are L3-temporal hits.

template <int K, int NN, int NY, int SP>
__global__ __launch_bounds__(512, 4) void k_gemm_t(const bf16* __restrict__ A,
                                                   const bf16* __restrict__ B2,
                                                   bf16* __restrict__ C,
                                                   const float* __restrict__ as_,
                                                   const float* __restrict__ ad_,
                                                   float* __restrict__ al_s,
                                                   float* __restrict__ al_d,
                                                   int N) {
  constexpr int nk = K / 32;
  constexpr int nfr = NN >> 4;
  __shared__ __align__(16) char smem[34816];         // main: 2x16KB dbuf; epi: 128x272B
  int t = threadIdx.x;
  int wv = t >> 6, lane = t & 63;
  int mg = wv >> 1, ng = wv & 1;
  int quad = lane >> 4, l15 = lane & 15;
  int bid = blockIdx.x;
  int hd = bid % NY;                                  // y-fastest: siblings adjacent
  size_t bm0 = (size_t)(bid / NY) * 256;
  int ctb = hd * 8 + ng * 4;                          // first 16-col tile
  int coff = hd * 128;                                // block col origin

  // staging map: thread t covers slab row sr (+128 for shot 1), slot p.
  // source chunk c = p ^ swz(sr); swz(r) = (r&3) ^ ((r>>2)&3). Both terms are
  // invariant under +128, so one c serves both shots.
  int sr = t >> 2, p = t & 3;
  int c = p ^ (sr & 3) ^ ((sr >> 2) & 3);
  const bf16* g0 = A + (bm0 + sr) * (size_t)K + c * 8;
  const bf16* g1 = g0 + (size_t)128 * K;
  const bf16* Bp = B2 + ((size_t)ctb << 9) + lane * 8;
  char* sA0 = smem;
  char* sA1 = smem + 16384;

  f4v acc[4][4];
#pragma unroll
  for (int ms = 0; ms < 4; ++ms)
#pragma unroll
    for (int bn = 0; bn < 4; ++bn) acc[ms][bn] = f4v{0, 0, 0, 0};

#define STAGE(step, bufp)                                                       \
  do {                                                                          \
    __builtin_amdgcn_global_load_lds(                                           \
        (const __attribute__((address_space(1))) void*)(g0 + (step) * 32),      \
        (__attribute__((address_space(3))) void*)((bufp) + wv * 1024),          \
        16, 0, 0);                                                              \
    __builtin_amdgcn_global_load_lds(                                           \
        (const __attribute__((address_space(1))) void*)(g1 + (step) * 32),      \
        (__attribute__((address_space(3))) void*)((bufp) + 8192 + wv * 1024),   \
        16, 0, 0);                                                              \
  } while (0)

  STAGE(0, sA0);
  __syncthreads();                       // vmcnt(0): tile 0 landed

  for (int ik = 0; ik < nk; ++ik) {
    int cur = ik & 1;
    if (ik + 1 < nk) STAGE(ik + 1, cur ? sA0 : sA1);   // issue next tile FIRST

    const char* sb = cur ? sA1 : sA0;
    s8v af[4];
#pragma unroll
    for (int ms = 0; ms < 4; ++ms) {
      int row = mg * 64 + ms * 16 + l15;
      int pos = quad ^ (row & 3) ^ ((row >> 2) & 3);
      af[ms] = *(const s8v*)(sb + row * 64 + pos * 16);
    }
    s8v pb[4];
#pragma unroll
    for (int bn = 0; bn < 4; ++bn)
      pb[bn] = *(const s8v*)(Bp + ((size_t)(ik * nfr + bn) << 9));
#pragma unroll
    for (int ms = 0; ms < 4; ++ms)
#pragma unroll
      for (int bn = 0; bn < 4; ++bn)
        acc[ms][bn] = __builtin_amdgcn_mfma_f32_16x16x32_bf16(af[ms], pb[bn], acc[ms][bn], 0, 0, 0);

    __syncthreads();                     // drain stage(t+1) + guard buffer reuse
  }
#undef STAGE

  // -------- epilogue: LDS-staged C + fused attention logits (no atomics) -----
  // C/D layout: col = lane&15, row = quad*4 + reg  [m89/m91 verified]
  short* stg = (short*)smem;             // [128 rows][136 shorts] (272B stride)
  const float* asb = as_ + coff;
  const float* adb = ad_ + coff;
#pragma unroll
  for (int ph = 0; ph < 2; ++ph) {
    if ((mg >> 1) == ph) {               // waves owning rows ph*128..+127
      int rbase = (mg & 1) * 64;
#pragma unroll
      for (int ms = 0; ms < 4; ++ms)
#pragma unroll
        for (int bn = 0; bn < 4; ++bn) {
          int cl = (ng * 4 + bn) * 16 + l15;
#pragma unroll
          for (int r = 0; r < 4; ++r) {
            int rl = rbase + ms * 16 + quad * 4 + r;
            bf16 b = __float2bfloat16(acc[ms][bn][r]);
            stg[rl * 136 + cl] = *(short*)&b;
          }
        }
    }
    __syncthreads();
    // read-out: 2048 16B-chunks; 16 consecutive lanes cover one 256B row.
#pragma unroll
    for (int k2 = 0; k2 < 4; ++k2) {
      int cid = k2 * 512 + t;
      int row = cid >> 4, ch = cid & 15;
      s8v v = *(const s8v*)&stg[row * 136 + ch * 8];
      size_t rowg = bm0 + ph * 128 + row;
      *(s8v*)&C[rowg * NN + coff + ch * 8] = v;   // full-line coalesced store
      float4 a0 = *(const float4*)(asb + ch * 8);
      float4 a1 = *(const float4*)(asb + ch * 8 + 4);
      float4 d0 = *(const float4*)(adb + ch * 8);
      float4 d1 = *(const float4*)(adb + ch * 8 + 4);
      float ps = b2f(v[0]) * a0.x + b2f(v[1]) * a0.y + b2f(v[2]) * a0.z + b2f(v[3]) * a0.w
               + b2f(v[4]) * a1.x + b2f(v[5]) * a1.y + b2f(v[6]) * a1.z + b2f(v[7]) * a1.w;
      float pd = b2f(v[0]) * d0.x + b2f(v[1]) * d0.y + b2f(v[2]) * d0.z + b2f(v[3]) * d0.w
               + b2f(v[4]) * d1.x + b2f(v[5]) * d1.y + b2f(v[6]) * d1.z + b2f(v[7]) * d1.w;
#pragma unroll
      for (int off = 1; off <= 8; off <<= 1) {
        ps += __shfl_xor(ps, off, 64);
        pd += __shfl_xor(pd, off, 64);
      }
      if (ch == 0 && rowg < (size_t)N) {
        al_s[rowg * SP + hd] = ps;       // one head per y-block: plain store
        al_d[rowg * SP + hd] = pd;
      }
    }
    __syncthreads();
  }
}

// -------- fused segment-softmax + weighted aggregation: one wave per node --------
// (stable at ~241us/layer across 7 rounds; at the random-gather L2-miss floor.)

template <int CPL> struct HVec;
template <> struct HVec<8> { typedef s8v T; };
template <> struct HVec<4> { typedef s4v T; };

template <int H, typename OT>
__global__ __launch_bounds__(256) void k_attn_agg(const bf16* __restrict__ hbuf,
                           const int* __restrict__ ssrc,
                           const int* __restrict__ offs, const float* __restrict__ al_s,
                           const float* __restrict__ al_d, const float* __restrict__ bias,
                           OT* __restrict__ out, int N) {
  constexpr int SW  = (H > 1) ? 4 : 2;   // stash record (floats)
  constexpr int ROW = H * 128;           // channels per node row
  constexpr int CPL = (H > 1) ? 8 : 4;   // channels per active lane
  constexpr int NL  = ROW / CPL;         // active lanes (48 or 32)
  typedef typename HVec<CPL>::T hvec;

  __shared__ __align__(16) float stash[4][64 * SW];
  int n = (blockIdx.x * blockDim.x + threadIdx.x) >> 6;
  int lane = threadIdx.x & 63;
  if (n >= N) return;
  float* st = stash[threadIdx.x >> 6];
  int start = offs[n], end = offs[n + 1];

  float ald[H];
  if constexpr (H > 1) {
    float4 t = *(const float4*)&al_d[(size_t)n * 4];
    ald[0] = t.x; ald[1] = t.y; ald[2] = t.z;
  } else {
    ald[0] = al_d[n];
  }

  bool act = lane < NL;
  int c0 = act ? lane * CPL : 0;
  int hd_l = c0 >> 7;                    // this lane's head (0 for idle lanes)

  float m[H];
  float den = 0.f;                       // own-head denominator
  float acc[CPL];
#pragma unroll
  for (int hd = 0; hd < H; ++hd) m[hd] = -1e30f;
#pragma unroll
  for (int i = 0; i < CPL; ++i) acc[i] = 0.f;

  for (int cb = start; cb < end; cb += 64) {
    int cl = end - cb; if (cl > 64) cl = 64;
    bool el = lane < cl;
    int mys = el ? ssrc[cb + lane] : 0;
    float ev[H];
    if constexpr (H > 1) {
      float4 av = *(const float4*)&al_s[(size_t)mys * 4];
      ev[0] = av.x; ev[1] = av.y; ev[2] = av.z;
    } else {
      ev[0] = al_s[mys];
    }
#pragma unroll
    for (int hd = 0; hd < H; ++hd)
      ev[hd] = el ? lrelu(ev[hd] + ald[hd]) : -1e30f;

    // chunk max (fused -- no separate max pass over the edges)
    float nm[H];
#pragma unroll
    for (int hd = 0; hd < H; ++hd) {
      float v = ev[hd];
#pragma unroll
      for (int off = 32; off; off >>= 1) v = fmaxf(v, __shfl_xor(v, off, 64));
      nm[hd] = fmaxf(v, m[hd]);
    }
    if (cb > start) {                    // online rescale; wave-uniform branch
      float sc[H];
#pragma unroll
      for (int hd = 0; hd < H; ++hd) sc[hd] = __expf(m[hd] - nm[hd]);
      float so = sc[hd_l];
      den *= so;
#pragma unroll
      for (int i = 0; i < CPL; ++i) acc[i] *= so;
    }
#pragma unroll
    for (int hd = 0; hd < H; ++hd) m[hd] = nm[hd];

    float myex[H];
#pragma unroll
    for (int hd = 0; hd < H; ++hd) myex[hd] = el ? __expf(ev[hd] - m[hd]) : 0.f;

    // stash this chunk's edge records (wave-private region; wave-synchronous)
    __builtin_amdgcn_wave_barrier();
    if constexpr (H > 1) {
      float4 s4{__int_as_float(mys), myex[0], myex[1], myex[2]};
      *(float4*)&st[lane * 4] = s4;
    } else {
      float2 s2{__int_as_float(mys), myex[0]};
      *(float2*)&st[lane * 2] = s2;
    }
    asm volatile("s_waitcnt lgkmcnt(0)" ::: "memory");
    __builtin_amdgcn_wave_barrier();

    for (int r = 0; r < cl; r += 8) {
      int su[8]; float a[8];
#pragma unroll
      for (int u = 0; u < 8; ++u) {
        if constexpr (H > 1) {
          float4 ed = *(const float4*)&st[(r + u) * 4];   // broadcast ds_read_b128
          su[u] = __float_as_int(ed.x);
          a[u] = (hd_l == 0) ? ed.y : ((hd_l == 1) ? ed.z : ed.w);
        } else {
          float2 ed = *(const float2*)&st[(r + u) * 2];
          su[u] = __float_as_int(ed.x);
          a[u] = ed.y;
        }
        den += a[u];                     // tail slots stash a==0
      }
      hvec hv[8];
#pragma unroll
      for (int u = 0; u < 8; ++u)
        hv[u] = *(const hvec*)(hbuf + (size_t)su[u] * ROW + c0);
#pragma unroll
      for (int u = 0; u < 8; ++u)
#pragma unroll
        for (int i = 0; i < CPL; ++i)
          acc[i] += a[u] * b2f(hv[u][i]);
    }
  }

  if (act) {
    float rr = 1.f / (den + 1e-16f);
    u4v srd = make_srd(out);
    int boff = (int)(((size_t)n * ROW + c0) * sizeof(OT));
    if constexpr (sizeof(OT) == 2) {
      union { s8v s; i4v i; } u;
#pragma unroll
      for (int i = 0; i < CPL; ++i) {
        float o = lrelu(acc[i] * rr + bias[c0 + i]);
        bf16 b = __float2bfloat16(o);
        u.s[i] = *(short*)&b;
      }
      bstore16_nt(srd, boff, u.i);
    } else {
      union { float4 f; i4v i; } u;
      u.f.x = lrelu(acc[0] * rr + bias[c0 + 0]);
      u.f.y = lrelu(acc[1] * rr + bias[c0 + 1]);
      u.f.z = lrelu(acc[2] * rr + bias[c0 + 2]);
      u.f.w = lrelu(acc[3] * rr + bias[c0 + 3]);
      bstore16_nt(srd, boff, u.i);
    }
  }
}

// ---------------- global mean pool: one wave per graph, no atomics ----------------

__global__ void k_pool(const float* __restrict__ h, const int* __restrict__ goffs,
                       float* __restrict__ out, int G) {
  int g = (blockIdx.x * blockDim.x + threadIdx.x) >> 6;
  int lane = threadIdx.x & 63;
  if (g >= G) return;
  int s = goffs[g], e = goffs[g + 1];
  float ax = 0.f, ay = 0.f;
  for (int n = s; n < e; ++n) {
    float2 v = *(const float2*)&h[(size_t)n * 128 + lane * 2];
    ax += v.x; ay += v.y;
  }
  float c = fmaxf((float)(e - s), 1.f);
  st2(&out[(size_t)g * 128 + lane * 2], ax / c, ay / c);
}

// ---------------- host launcher ----------------

extern "C" void kernel_launch(void* const* d_in, const int* in_sizes, int n_in,
                              void* d_out, int out_size, void* d_ws, size_t ws_size,
                              hipStream_t stream) {
  const float* x   = (const float*)d_in[0];
  const int*   ei  = (const int*)d_in[1];
  const int*   bat = (const int*)d_in[2];
  const float* W1  = (const float*)d_in[3];
  const float* a1s = (const float*)d_in[4];
  const float* a1d = (const float*)d_in[5];
  const float* b1  = (const float*)d_in[6];
  const float* W2  = (const float*)d_in[7];
  const float* a2s = (const float*)d_in[8];
  const float* a2d = (const float*)d_in[9];
  const float* b2  = (const float*)d_in[10];
  const float* W3  = (const float*)d_in[11];
  const float* a3s = (const float*)d_in[12];
  const float* a3d = (const float*)d_in[13];
  const float* b3  = (const float*)d_in[14];
  float* out = (float*)d_out;

  const int N = in_sizes[2];          // 200000
  const int E = in_sizes[1] / 2;      // 1600000
  const int Et = E + N;               // with self-loops
  const int G = out_size / 128;       // 5000

  const int MB = (N + 255) / 256;     // 256-row GEMM blocks
  const int Mpad = MB * 256;          // padded rows (tail rows are owned garbage)

  // ---- workspace carve (bf16 intermediates; buffers padded to Mpad rows) ----
  char* p = (char*)d_ws;
  auto carve = [&](size_t bytes) { void* r = (void*)p; p += (bytes + 255) & ~(size_t)255; return r; };
  bf16*  bufA   = (bf16*)carve((size_t)Mpad * 384 * 2);  // agg out / GEMM A; also hosts xb & fp32 layer-3 out
  bf16*  bufB   = (bf16*)carve((size_t)Mpad * 384 * 2);  // GEMM output h
  float* al_s   = (float*)carve((size_t)N * 4 * 4);      // padded to 4 floats/node
  float* al_d   = (float*)carve((size_t)N * 4 * 4);
  int*   ssrc   = (int*)carve((size_t)Et * 4);
  int*   offs   = (int*)carve((size_t)(N + 1) * 4);
  int*   deg    = (int*)carve((size_t)N * 4);
  int*   cur    = (int*)carve((size_t)N * 4);
  int*   bsum   = (int*)carve(4096 * 4);
  int*   gdeg   = (int*)carve((size_t)G * 4);
  int*   goffs  = (int*)carve((size_t)(G + 1) * 4);
  bf16*  Wp1    = (bf16*)carve((size_t)384 * 128 * 2);   // packed B2 buffers
  bf16*  Wp2    = (bf16*)carve((size_t)384 * 384 * 2);
  bf16*  Wp3    = (bf16*)carve((size_t)128 * 384 * 2);
  size_t need = (size_t)(p - (char*)d_ws);

  if (ws_size < need) {
    k_zero_out<<<(out_size + 255) / 256, 256, 0, stream>>>(out, out_size);
    return;
  }

  const int* esrc = ei;
  const int* edst = ei + E;

  int ebl = (Et + 255) / 256;
  int NB = (N + 1023) / 1024;
  int GB = (G + 1023) / 1024;
  int nodeWaveBlocks = (N * 64 + 255) / 256;

  // ---- prep: weight pack+cast, x cast (xb aliases bufA) ----
  bf16* xb = bufA;
  k_cvt<<<((long)N * 128 / 8 + 255) / 256, 256, 0, stream>>>(x, xb, (long)N * 128 / 8);
  k_tw2<<<(128 * 384 / 8 + 255) / 256, 256, 0, stream>>>(W1, Wp1, 128, 384);
  k_tw2<<<(384 * 384 / 8 + 255) / 256, 256, 0, stream>>>(W2, Wp2, 384, 384);
  k_tw2<<<(384 * 128 / 8 + 255) / 256, 256, 0, stream>>>(W3, Wp3, 384, 128);

  // ---- sort edges by dst ----
  k_zero<<<(N + 255) / 256, 256, 0, stream>>>((unsigned int*)deg, N);
  k_hist<<<ebl, 256, 0, stream>>>(edst, deg, E, Et);
  k_scan1<<<NB, 256, 0, stream>>>(deg, offs, bsum, N);
  k_scan2<<<1, 256, 0, stream>>>(bsum, NB);
  k_scan3<<<NB, 256, 0, stream>>>(offs, bsum, N, Et);
  k_zero<<<(N + 255) / 256, 256, 0, stream>>>((unsigned int*)cur, N);
  k_scatter<<<ebl, 256, 0, stream>>>(esrc, edst, offs, cur, ssrc, E, Et);

  // ---- graph offsets for pool (batch is sorted) ----
  k_zero<<<(G + 255) / 256, 256, 0, stream>>>((unsigned int*)gdeg, G);
  k_hist1<<<(N + 255) / 256, 256, 0, stream>>>(bat, gdeg, N);
  k_scan1<<<GB, 256, 0, stream>>>(gdeg, goffs, bsum, G);
  k_scan2<<<1, 256, 0, stream>>>(bsum, GB);
  k_scan3<<<GB, 256, 0, stream>>>(goffs, bsum, G, N);

  // ---- layer 1: xb[N,128] @ W1 -> bufB[N,384] (+fused al, no atomics) ----
  k_gemm_t<128, 384, 3, 4><<<MB * 3, 512, 0, stream>>>(xb, Wp1, bufB, a1s, a1d, al_s, al_d, N);
  k_attn_agg<3, bf16><<<nodeWaveBlocks, 256, 0, stream>>>(bufB, ssrc, offs, al_s, al_d, b1, bufA, N);

  // ---- layer 2: bufA[N,384] @ W2 -> bufB[N,384] (+fused al) ----
  k_gemm_t<384, 384, 3, 4><<<MB * 3, 512, 0, stream>>>(bufA, Wp2, bufB, a2s, a2d, al_s, al_d, N);
  k_attn_agg<3, bf16><<<nodeWaveBlocks, 256, 0, stream>>>(bufB, ssrc, offs, al_s, al_d, b2, bufA, N);

  // ---- layer 3: bufA[N,384] @ W3 -> bufB[N,128], heads=1, fp32 agg out ----
  k_gemm_t<384, 128, 1, 1><<<MB, 512, 0, stream>>>(bufA, Wp3, bufB, a3s, a3d, al_s, al_d, N);
  float* out3 = (float*)bufA;
  k_attn_agg<1, float><<<nodeWaveBlocks, 256, 0, stream>>>(bufB, ssrc, offs, al_s, al_d, b3, out3, N);

  // ---- global mean pool: segmented, atomic-free ----
  k_pool<<<(G * 64 + 255) / 256, 256, 0, stream>>>(out3, goffs, out, G);
}